// Round 5
// baseline (90.286 us; speedup 1.0000x reference)
//
#include <hip/hip_runtime.h>
#include <math.h>

#define TS 64
#define T 64
#define K 256
#define NSEG 4
#define KSEG 64
#define IMG_W 512

// Single fused kernel. 1024 blocks x 512 threads (8 waves -> 4 blocks/CU,
// 32 waves/CU = full occupancy).
//
// Stage phase: threads 0..255 each compute one packed gaussian record for
// this block's tile into LDS (the former pack_kernel's math, done redundantly
// by the 16 blocks of a tile -- ~70 cyc amortized over a ~4500 cyc k-loop,
// and it removes the pack kernel launch + d_ws round-trip entirely).
//   alpha_raw = op*exp(-0.5*maha) = exp2(ea*dx^2 + eb*dx*dy + ed*dy^2 + lop)
//   s = -0.5*log2(e)/det: ea=s*d, eb=-s*(b+c), ed=s*a, lop=log2(op)
//
// Render phase: seg = tid>>7 (0..3) handles k=[seg*64, seg*64+64) for the
// same 256 pixels; each thread renders 2 pixels (rows lrow, lrow+2) sharing
// the dx column terms. k-loop data comes from LDS broadcast reads
// (same-address across all 64 lanes -> conflict-free, ~29 cyc DS/iter,
// hidden under ~70 cyc VALU/iter) instead of scalar loads, removing the
// serialized s_load latency chain that left ~10us of stall in R4.
//
// Segment combine (linear decomposition of alpha compositing):
//   C = C_0 + sum_{s>=1} (C_s_local - S_prev(s) * A_s)
//   A_s = sum alpha_k*col_k;  S_prev(s) = sum of earlier segs' alpha sums.
__global__ __launch_bounds__(512, 8) void render_fused(
    const float* __restrict__ mu, const float* __restrict__ cov,
    const float* __restrict__ opacity, const float* __restrict__ color,
    const int* __restrict__ tile_idx, float* __restrict__ out) {
  __shared__ float4 sA[K];            // mux, muy, ea, eb
  __shared__ float4 sB[K];            // ed, lop, cr, cg
  __shared__ float sC[K];             // cb
  __shared__ float sS[NSEG][128][2];  // per-seg alpha sums, 2 px/thread
  __shared__ float sD[3][128][6];     // segs 1..3 final contributions

  int blk = blockIdx.x;
  int tile = blk & 63;
  int chunk = blk >> 6;  // 0..15, 4 pixel-rows each
  int tid = threadIdx.x;

  if (tid < K) {
    int n = tile_idx[tile * K + tid];
    float a = cov[4 * n + 0];
    float b = cov[4 * n + 1];
    float c = cov[4 * n + 2];
    float d = cov[4 * n + 3];
    float det = fmaxf(a * d - b * c, 1e-6f);
    const float LOG2E = 1.4426950408889634f;
    float s = -0.5f * LOG2E / det;
    sA[tid] = make_float4(mu[2 * n], mu[2 * n + 1], s * d, -s * (b + c));
    sB[tid] = make_float4(s * a, log2f(fmaxf(opacity[n], 1e-30f)),
                          color[3 * n], color[3 * n + 1]);
    sC[tid] = color[3 * n + 2];
  }
  __syncthreads();

  int seg = __builtin_amdgcn_readfirstlane(tid) >> 7;  // wave-uniform 0..3
  int pslot = tid & 127;
  int lx = pslot & 63;
  int lrow = pslot >> 6;  // 0..1; this thread's rows: lrow, lrow+2 of chunk
  int ty = tile >> 3, tx = tile & 7;
  int ly0 = chunk * 4 + lrow;
  float px = (float)(tx * TS + lx) + 0.5f;
  float py0 = (float)(ty * TS + ly0) + 0.5f;  // second pixel: py0 + 2

  const int kb = seg * KSEG;

  float c0r = 0, c0g = 0, c0b = 0, c1r = 0, c1g = 0, c1b = 0;
  float a0r = 0, a0g = 0, a0b = 0, a1r = 0, a1g = 0, a1b = 0;
  float S0 = 0, S1 = 0;

  if (seg == 0) {
#pragma unroll 8
    for (int k = 0; k < KSEG; ++k) {
      float4 A = sA[kb + k];
      float4 B = sB[kb + k];
      float cb = sC[kb + k];
      float dx = px - A.x;
      float tb = A.w * dx;
      float base = fmaf(A.z * dx, dx, B.y);
      float dy0 = py0 - A.y;
      float dy1 = dy0 + 2.0f;
      float m0 = fmaf(dy0, fmaf(B.x, dy0, tb), base);
      float m1 = fmaf(dy1, fmaf(B.x, dy1, tb), base);
      float al0 = fminf(fmaxf(__builtin_amdgcn_exp2f(m0), 0.01f), 0.99f);
      float al1 = fminf(fmaxf(__builtin_amdgcn_exp2f(m1), 0.01f), 0.99f);
      float w0 = fmaf(-al0, S0, al0);
      float w1 = fmaf(-al1, S1, al1);
      c0r = fmaf(w0, B.z, c0r);
      c0g = fmaf(w0, B.w, c0g);
      c0b = fmaf(w0, cb, c0b);
      c1r = fmaf(w1, B.z, c1r);
      c1g = fmaf(w1, B.w, c1g);
      c1b = fmaf(w1, cb, c1b);
      S0 += al0;
      S1 += al1;
    }
  } else {
#pragma unroll 8
    for (int k = 0; k < KSEG; ++k) {
      float4 A = sA[kb + k];
      float4 B = sB[kb + k];
      float cb = sC[kb + k];
      float dx = px - A.x;
      float tb = A.w * dx;
      float base = fmaf(A.z * dx, dx, B.y);
      float dy0 = py0 - A.y;
      float dy1 = dy0 + 2.0f;
      float m0 = fmaf(dy0, fmaf(B.x, dy0, tb), base);
      float m1 = fmaf(dy1, fmaf(B.x, dy1, tb), base);
      float al0 = fminf(fmaxf(__builtin_amdgcn_exp2f(m0), 0.01f), 0.99f);
      float al1 = fminf(fmaxf(__builtin_amdgcn_exp2f(m1), 0.01f), 0.99f);
      float w0 = fmaf(-al0, S0, al0);
      float w1 = fmaf(-al1, S1, al1);
      c0r = fmaf(w0, B.z, c0r);
      c0g = fmaf(w0, B.w, c0g);
      c0b = fmaf(w0, cb, c0b);
      c1r = fmaf(w1, B.z, c1r);
      c1g = fmaf(w1, B.w, c1g);
      c1b = fmaf(w1, cb, c1b);
      a0r = fmaf(al0, B.z, a0r);
      a0g = fmaf(al0, B.w, a0g);
      a0b = fmaf(al0, cb, a0b);
      a1r = fmaf(al1, B.z, a1r);
      a1g = fmaf(al1, B.w, a1g);
      a1b = fmaf(al1, cb, a1b);
      S0 += al0;
      S1 += al1;
    }
  }

  sS[seg][pslot][0] = S0;
  sS[seg][pslot][1] = S1;
  __syncthreads();

  float Sp0 = 0.f, Sp1 = 0.f;
  if (seg >= 1) { Sp0 += sS[0][pslot][0]; Sp1 += sS[0][pslot][1]; }
  if (seg >= 2) { Sp0 += sS[1][pslot][0]; Sp1 += sS[1][pslot][1]; }
  if (seg >= 3) { Sp0 += sS[2][pslot][0]; Sp1 += sS[2][pslot][1]; }
  if (seg >= 1) {
    sD[seg - 1][pslot][0] = fmaf(-Sp0, a0r, c0r);
    sD[seg - 1][pslot][1] = fmaf(-Sp0, a0g, c0g);
    sD[seg - 1][pslot][2] = fmaf(-Sp0, a0b, c0b);
    sD[seg - 1][pslot][3] = fmaf(-Sp1, a1r, c1r);
    sD[seg - 1][pslot][4] = fmaf(-Sp1, a1g, c1g);
    sD[seg - 1][pslot][5] = fmaf(-Sp1, a1b, c1b);
  }
  __syncthreads();

  if (seg == 0) {
    float f0r = c0r + sD[0][pslot][0] + sD[1][pslot][0] + sD[2][pslot][0];
    float f0g = c0g + sD[0][pslot][1] + sD[1][pslot][1] + sD[2][pslot][1];
    float f0b = c0b + sD[0][pslot][2] + sD[1][pslot][2] + sD[2][pslot][2];
    float f1r = c1r + sD[0][pslot][3] + sD[1][pslot][3] + sD[2][pslot][3];
    float f1g = c1g + sD[0][pslot][4] + sD[1][pslot][4] + sD[2][pslot][4];
    float f1b = c1b + sD[0][pslot][5] + sD[1][pslot][5] + sD[2][pslot][5];
    int x = tx * TS + lx;
    int y0 = ty * TS + ly0;
    size_t o0 = ((size_t)y0 * IMG_W + x) * 3;
    size_t o1 = o0 + (size_t)2 * IMG_W * 3;  // row ly0+2
    out[o0 + 0] = f0r;
    out[o0 + 1] = f0g;
    out[o0 + 2] = f0b;
    out[o1 + 0] = f1r;
    out[o1 + 1] = f1g;
    out[o1 + 2] = f1b;
  }
}

extern "C" void kernel_launch(void* const* d_in, const int* in_sizes, int n_in,
                              void* d_out, int out_size, void* d_ws,
                              size_t ws_size, hipStream_t stream) {
  const float* mu = (const float*)d_in[0];
  const float* cov = (const float*)d_in[1];
  const float* opacity = (const float*)d_in[2];
  const float* color = (const float*)d_in[3];
  const int* tile_idx = (const int*)d_in[4];
  float* out = (float*)d_out;
  (void)d_ws;
  (void)ws_size;

  render_fused<<<T * 16, 512, 0, stream>>>(mu, cov, opacity, color, tile_idx,
                                           out);
}

// Round 6
// 88.410 us; speedup vs baseline: 1.0212x; 1.0212x over previous
//
#include <hip/hip_runtime.h>
#include <math.h>

#define TS 64
#define T 64
#define K 256
#define NSEG 4
#define KSEG 64
#define IMG_W 512

// Fused single kernel. 512 blocks x 512 threads (8 waves; launch_bounds
// (512,4) -> 2 blocks/CU = 16 waves/CU = 4 waves/SIMD, VGPR cap 128).
//
// Stage: threads 0..255 build one 32-B record each in LDS:
//   sA[k] = {mux, muy, ea, eb}
//   sB[k] = {ed, lop, bf16(cr)|bf16(cg)<<16 (bitcast), cb}
//   alpha_raw = op*exp(-0.5*maha) = exp2(ea*dx^2 + eb*dx*dy + ed*dy^2 + lop)
//   s = -0.5*log2(e)/det: ea=s*d, eb=-s*(b+c), ed=s*a, lop=log2(op)
// 32-B record -> exactly 2 ds_read_b128 per k-iteration (DS pipe was the
// R5 bottleneck at ~30 cyc/iter x 524k wave-iters = 25.6us/CU).
//
// Render: seg = tid>>7 (0..3, wave-uniform) handles k=[seg*64, seg*64+64).
// Each thread renders 4 pixels in one column (rows ly0..ly0+3): dx terms and
// both DS reads amortize over 4 px -> wave-iters halve vs R5.
//
// Segment combine (additive transmittance, trans_k = 1 - sum_{j<k} alpha_j):
//   C = C_0 + sum_{s>=1} (C_s_local - S_prev(s) * A_s)
//   A_s = sum alpha_k*col_k;  S_prev(s) = sum of earlier segs' alpha sums.
__global__ __launch_bounds__(512, 4) void render_fused(
    const float* __restrict__ mu, const float* __restrict__ cov,
    const float* __restrict__ opacity, const float* __restrict__ color,
    const int* __restrict__ tile_idx, float* __restrict__ out) {
  __shared__ float4 sA[K];
  __shared__ float4 sB[K];
  __shared__ float sS[NSEG][128][4];   // per-seg alpha sums, 4 px/thread
  __shared__ float sD[3][128][4][3];   // segs 1..3 corrected contributions

  int blk = blockIdx.x;
  int tile = blk & 63;   // XCD affinity: tile%8 == blk%8
  int chunk = blk >> 6;  // 0..7, 8 pixel-rows each
  int tid = threadIdx.x;

  if (tid < K) {
    int n = tile_idx[tile * K + tid];
    float a = cov[4 * n + 0];
    float b = cov[4 * n + 1];
    float c = cov[4 * n + 2];
    float d = cov[4 * n + 3];
    float det = fmaxf(a * d - b * c, 1e-6f);
    const float LOG2E = 1.4426950408889634f;
    float s = -0.5f * LOG2E / det;
    unsigned crb = (__float_as_uint(color[3 * n + 0]) + 0x8000u) >> 16;
    unsigned cgb = (__float_as_uint(color[3 * n + 1]) + 0x8000u) >> 16;
    sA[tid] = make_float4(mu[2 * n], mu[2 * n + 1], s * d, -s * (b + c));
    sB[tid] = make_float4(s * a, log2f(fmaxf(opacity[n], 1e-30f)),
                          __uint_as_float(crb | (cgb << 16)),
                          color[3 * n + 2]);
  }
  __syncthreads();

  int seg = __builtin_amdgcn_readfirstlane(tid) >> 7;  // wave-uniform 0..3
  int pslot = tid & 127;
  int lx = pslot & 63;
  int half = pslot >> 6;              // 0..1
  int ty = tile >> 3, tx = tile & 7;
  int ly0 = chunk * 8 + half * 4;     // this thread: rows ly0..ly0+3
  float px = (float)(tx * TS + lx) + 0.5f;
  float py0 = (float)(ty * TS + ly0) + 0.5f;

  const int kb = seg * KSEG;

  float C[4][3] = {};
  float Aa[4][3] = {};
  float S[4] = {};

  if (seg == 0) {
#pragma unroll 4
    for (int k = 0; k < KSEG; ++k) {
      float4 A4 = sA[kb + k];
      float4 B4 = sB[kb + k];
      unsigned cc = __float_as_uint(B4.z);
      float cr = __uint_as_float(cc << 16);
      float cg = __uint_as_float(cc & 0xffff0000u);
      float cb = B4.w;
      float dx = px - A4.x;
      float tb = A4.w * dx;
      float base = fmaf(A4.z * dx, dx, B4.y);
      float dy = py0 - A4.y;
#pragma unroll
      for (int p = 0; p < 4; ++p) {
        float dyp = dy + (float)p;
        float m = fmaf(dyp, fmaf(B4.x, dyp, tb), base);
        float al = fminf(fmaxf(__builtin_amdgcn_exp2f(m), 0.01f), 0.99f);
        float w = fmaf(-al, S[p], al);
        C[p][0] = fmaf(w, cr, C[p][0]);
        C[p][1] = fmaf(w, cg, C[p][1]);
        C[p][2] = fmaf(w, cb, C[p][2]);
        S[p] += al;
      }
    }
  } else {
#pragma unroll 4
    for (int k = 0; k < KSEG; ++k) {
      float4 A4 = sA[kb + k];
      float4 B4 = sB[kb + k];
      unsigned cc = __float_as_uint(B4.z);
      float cr = __uint_as_float(cc << 16);
      float cg = __uint_as_float(cc & 0xffff0000u);
      float cb = B4.w;
      float dx = px - A4.x;
      float tb = A4.w * dx;
      float base = fmaf(A4.z * dx, dx, B4.y);
      float dy = py0 - A4.y;
#pragma unroll
      for (int p = 0; p < 4; ++p) {
        float dyp = dy + (float)p;
        float m = fmaf(dyp, fmaf(B4.x, dyp, tb), base);
        float al = fminf(fmaxf(__builtin_amdgcn_exp2f(m), 0.01f), 0.99f);
        float w = fmaf(-al, S[p], al);
        C[p][0] = fmaf(w, cr, C[p][0]);
        C[p][1] = fmaf(w, cg, C[p][1]);
        C[p][2] = fmaf(w, cb, C[p][2]);
        Aa[p][0] = fmaf(al, cr, Aa[p][0]);
        Aa[p][1] = fmaf(al, cg, Aa[p][1]);
        Aa[p][2] = fmaf(al, cb, Aa[p][2]);
        S[p] += al;
      }
    }
  }

#pragma unroll
  for (int p = 0; p < 4; ++p) sS[seg][pslot][p] = S[p];
  __syncthreads();

  if (seg >= 1) {
#pragma unroll
    for (int p = 0; p < 4; ++p) {
      float Sp = sS[0][pslot][p];
      if (seg >= 2) Sp += sS[1][pslot][p];
      if (seg >= 3) Sp += sS[2][pslot][p];
      sD[seg - 1][pslot][p][0] = fmaf(-Sp, Aa[p][0], C[p][0]);
      sD[seg - 1][pslot][p][1] = fmaf(-Sp, Aa[p][1], C[p][1]);
      sD[seg - 1][pslot][p][2] = fmaf(-Sp, Aa[p][2], C[p][2]);
    }
  }
  __syncthreads();

  if (seg == 0) {
    int x = tx * TS + lx;
#pragma unroll
    for (int p = 0; p < 4; ++p) {
      int y = ty * TS + ly0 + p;
      size_t o = ((size_t)y * IMG_W + x) * 3;
      out[o + 0] = C[p][0] + sD[0][pslot][p][0] + sD[1][pslot][p][0] +
                   sD[2][pslot][p][0];
      out[o + 1] = C[p][1] + sD[0][pslot][p][1] + sD[1][pslot][p][1] +
                   sD[2][pslot][p][1];
      out[o + 2] = C[p][2] + sD[0][pslot][p][2] + sD[1][pslot][p][2] +
                   sD[2][pslot][p][2];
    }
  }
}

extern "C" void kernel_launch(void* const* d_in, const int* in_sizes, int n_in,
                              void* d_out, int out_size, void* d_ws,
                              size_t ws_size, hipStream_t stream) {
  const float* mu = (const float*)d_in[0];
  const float* cov = (const float*)d_in[1];
  const float* opacity = (const float*)d_in[2];
  const float* color = (const float*)d_in[3];
  const int* tile_idx = (const int*)d_in[4];
  float* out = (float*)d_out;
  (void)d_ws;
  (void)ws_size;

  render_fused<<<T * 8, 512, 0, stream>>>(mu, cov, opacity, color, tile_idx,
                                          out);
}

// Round 7
// 72.861 us; speedup vs baseline: 1.2392x; 1.2134x over previous
//
#include <hip/hip_runtime.h>
#include <math.h>

#define TS 64
#define T 64
#define K 256
#define NSEG 4
#define KSEG 64
#define IMG_W 512

// d_ws layout (offsets in floats)
#define OFF_RA 0                       // float4[T*K]  {mux, muy, ea, eb}
#define OFF_RB (T * K * 4)             // float4[T*K]  {ed, lop, cr, cg}
#define OFF_RC (T * K * 8)             // float [T*K]  {cb}
#define OFF_PA (T * K * 9)             // float4[T*257] exclusive prefix of col
#define OFF_PK (OFF_PA + T * 257 * 4)  // float4[T*257] exclusive prefix of k*col
#define OFF_MASK (OFF_PK + T * 257 * 4)  // uint[T*16*8] per-band near bitmasks
// total ~287k floats = 1.15 MB << ws_size (>=268 MB per observed poison fill)

__device__ inline void scan256(float4* buf, int k) {
  for (int off = 1; off < 256; off <<= 1) {
    float4 t;
    bool act = (k >= off);
    if (act) t = buf[k - off];
    __syncthreads();
    if (act) {
      float4 u = buf[k];
      buf[k] = make_float4(u.x + t.x, u.y + t.y, u.z + t.z, 0.f);
    }
    __syncthreads();
  }
}

// Pass 1: one block per tile. Builds (a) packed records, (b) per-band
// (4-row x 64-col) conservative "near" bitmasks -- far => alpha == 0.01f
// exactly, since maha >= dist^2/trace(cov) and op*exp(-maha/2) <= 0.01 --
// and (c) exclusive prefix sums of col and k*col for O(1) far-run
// compositing (local trans is affine in k when every alpha == 0.01).
__global__ __launch_bounds__(256) void pack_kernel(
    const float* __restrict__ mu, const float* __restrict__ cov,
    const float* __restrict__ opacity, const float* __restrict__ color,
    const int* __restrict__ tile_idx, float* __restrict__ ws) {
  __shared__ float4 buf[256];
  __shared__ unsigned um[16 * 8];
  int tile = blockIdx.x;
  int k = threadIdx.x;
  int tx = tile & 7, ty = tile >> 3;
  if (k < 128) um[k] = 0u;

  int n = tile_idx[tile * K + k];
  float a = cov[4 * n + 0];
  float b = cov[4 * n + 1];
  float c = cov[4 * n + 2];
  float d = cov[4 * n + 3];
  float det = fmaxf(a * d - b * c, 1e-6f);
  const float LOG2E = 1.4426950408889634f;
  float s = -0.5f * LOG2E / det;
  float mux = mu[2 * n], muy = mu[2 * n + 1];
  float lop = log2f(fmaxf(opacity[n], 1e-30f));
  float cr = color[3 * n], cg = color[3 * n + 1], cb = color[3 * n + 2];

  float4* RA = (float4*)(ws + OFF_RA);
  float4* RB = (float4*)(ws + OFF_RB);
  float* RC = ws + OFF_RC;
  RA[tile * K + k] = make_float4(mux, muy, s * d, -s * (b + c));
  RB[tile * K + k] = make_float4(s * a, lop, cr, cg);
  RC[tile * K + k] = cb;

  // r^2 = 2*ln(op/0.01)*(a+d) = 2*ln2*(lop + log2(100))*(a+d), + safety
  float r2 = 1.3862943611f * (lop + 6.6438561898f) * (a + d);
  r2 = r2 * 1.0001f + 1e-3f;
  float x0 = tx * 64 + 0.5f, x1 = tx * 64 + 63.5f;
  float dxm = fmaxf(fmaxf(mux - x1, x0 - mux), 0.f);
  float dx2 = dxm * dxm;
  __syncthreads();  // um zeroed
  for (int bnd = 0; bnd < 16; ++bnd) {
    float y0 = ty * 64 + bnd * 4 + 0.5f;
    float y1 = y0 + 3.0f;
    float dym = fmaxf(fmaxf(muy - y1, y0 - muy), 0.f);
    float d2 = fmaf(dym, dym, dx2);
    if (d2 < r2) atomicOr(&um[bnd * 8 + (k >> 5)], 1u << (k & 31));
  }

  float4* PA = (float4*)(ws + OFF_PA);
  float4* PK = (float4*)(ws + OFF_PK);
  buf[k] = make_float4(cr, cg, cb, 0.f);
  __syncthreads();
  scan256(buf, k);
  if (k == 0) PA[tile * 257] = make_float4(0, 0, 0, 0);
  PA[tile * 257 + k + 1] = buf[k];  // exclusive at k+1
  __syncthreads();
  float fk = (float)k;
  buf[k] = make_float4(fk * cr, fk * cg, fk * cb, 0.f);
  __syncthreads();
  scan256(buf, k);
  if (k == 0) PK[tile * 257] = make_float4(0, 0, 0, 0);
  PK[tile * 257 + k + 1] = buf[k];
  __syncthreads();
  unsigned* gm = (unsigned*)(ws + OFF_MASK);
  if (k < 128) gm[tile * 128 + k] = um[k];
}

// Pass 2: 512 blocks x 512 threads. seg = tid>>7 handles k-range
// [seg*64, seg*64+64); each thread renders 4 pixels in one column.
// Wave = 64 cols x 4 rows band; its near-mask selects the ~1-3 gaussians
// needing full math; everything between collapses to O(1) runs.
// Segment combine: C = C_0 + sum_{s>=1}(C_s - S_prev(s)*A_s).
__global__ __launch_bounds__(512, 4) void render_kernel(
    const float* __restrict__ ws, float* __restrict__ out) {
  __shared__ float sS[NSEG][128][4];
  __shared__ float sD[3][128][4][3];

  int blk = blockIdx.x;
  int tile = blk & 63;
  int chunk = blk >> 6;  // 0..7
  int tid = threadIdx.x;
  int seg = __builtin_amdgcn_readfirstlane(tid >> 7);
  int pslot = tid & 127;
  int lx = pslot & 63;
  int bnd = __builtin_amdgcn_readfirstlane(chunk * 2 + ((tid >> 6) & 1));
  int ty = tile >> 3, tx = tile & 7;
  int ly0 = bnd * 4;
  float px = (float)(tx * 64 + lx) + 0.5f;
  float py0 = (float)(ty * 64 + ly0) + 0.5f;

  const float4* RA = (const float4*)(ws + OFF_RA) + tile * K;
  const float4* RB = (const float4*)(ws + OFF_RB) + tile * K;
  const float* RC = ws + OFF_RC + tile * K;
  const float4* PA = (const float4*)(ws + OFF_PA) + tile * 257;
  const float4* PK = (const float4*)(ws + OFF_PK) + tile * 257;
  const unsigned* gm =
      (const unsigned*)(ws + OFF_MASK) + tile * 128 + bnd * 8;

  const int kb = seg * KSEG;
  unsigned w0 = __builtin_amdgcn_readfirstlane(gm[kb >> 5]);
  unsigned w1 = __builtin_amdgcn_readfirstlane(gm[(kb >> 5) + 1]);
  unsigned long long m =
      (unsigned long long)w0 | ((unsigned long long)w1 << 32);

  float C[4][3] = {};
  float An[4][3] = {};
  float Af[3] = {0.f, 0.f, 0.f};
  float S[4] = {};

  int i = kb;
  while (true) {
    int j = (m != 0ULL) ? (kb + (int)__builtin_ctzll(m)) : (kb + KSEG);
    if (j > i) {  // far run [i, j): every alpha == 0.01 exactly
      float len = (float)(j - i);
      float4 paj = PA[j], pai = PA[i];
      float4 pkj = PK[j], pki = PK[i];
      float P1r = paj.x - pai.x, P1g = paj.y - pai.y, P1b = paj.z - pai.z;
      float fi = (float)i;
      float Rr = -1e-4f * fmaf(-fi, P1r, pkj.x - pki.x);
      float Rg = -1e-4f * fmaf(-fi, P1g, pkj.y - pki.y);
      float Rb = -1e-4f * fmaf(-fi, P1b, pkj.z - pki.z);
      Af[0] = fmaf(0.01f, P1r, Af[0]);
      Af[1] = fmaf(0.01f, P1g, Af[1]);
      Af[2] = fmaf(0.01f, P1b, Af[2]);
#pragma unroll
      for (int p = 0; p < 4; ++p) {
        float t = fmaf(-0.01f, S[p], 0.01f);  // 0.01*(1 - S_local)
        C[p][0] = fmaf(t, P1r, C[p][0]) + Rr;
        C[p][1] = fmaf(t, P1g, C[p][1]) + Rg;
        C[p][2] = fmaf(t, P1b, C[p][2]) + Rb;
        S[p] = fmaf(0.01f, len, S[p]);
      }
    }
    if (j >= kb + KSEG) break;
    // near gaussian k = j: full math
    float4 A4 = RA[j];
    float4 B4 = RB[j];
    float cbv = RC[j];
    float dx = px - A4.x;
    float tb = A4.w * dx;
    float base = fmaf(A4.z * dx, dx, B4.y);
    float dy = py0 - A4.y;
#pragma unroll
    for (int p = 0; p < 4; ++p) {
      float dyp = dy + (float)p;
      float mm = fmaf(dyp, fmaf(B4.x, dyp, tb), base);
      float al =
          __builtin_amdgcn_fmed3f(__builtin_amdgcn_exp2f(mm), 0.01f, 0.99f);
      float w = fmaf(-al, S[p], al);
      C[p][0] = fmaf(w, B4.z, C[p][0]);
      C[p][1] = fmaf(w, B4.w, C[p][1]);
      C[p][2] = fmaf(w, cbv, C[p][2]);
      An[p][0] = fmaf(al, B4.z, An[p][0]);
      An[p][1] = fmaf(al, B4.w, An[p][1]);
      An[p][2] = fmaf(al, cbv, An[p][2]);
      S[p] += al;
    }
    m &= (m - 1ULL);
    i = j + 1;
  }

#pragma unroll
  for (int p = 0; p < 4; ++p) sS[seg][pslot][p] = S[p];
  __syncthreads();

  if (seg >= 1) {
#pragma unroll
    for (int p = 0; p < 4; ++p) {
      float Sp = sS[0][pslot][p];
      if (seg >= 2) Sp += sS[1][pslot][p];
      if (seg >= 3) Sp += sS[2][pslot][p];
      sD[seg - 1][pslot][p][0] = fmaf(-Sp, An[p][0] + Af[0], C[p][0]);
      sD[seg - 1][pslot][p][1] = fmaf(-Sp, An[p][1] + Af[1], C[p][1]);
      sD[seg - 1][pslot][p][2] = fmaf(-Sp, An[p][2] + Af[2], C[p][2]);
    }
  }
  __syncthreads();

  if (seg == 0) {
    int x = tx * 64 + lx;
#pragma unroll
    for (int p = 0; p < 4; ++p) {
      int y = ty * 64 + ly0 + p;
      size_t o = ((size_t)y * IMG_W + x) * 3;
      out[o + 0] = C[p][0] + sD[0][pslot][p][0] + sD[1][pslot][p][0] +
                   sD[2][pslot][p][0];
      out[o + 1] = C[p][1] + sD[0][pslot][p][1] + sD[1][pslot][p][1] +
                   sD[2][pslot][p][1];
      out[o + 2] = C[p][2] + sD[0][pslot][p][2] + sD[1][pslot][p][2] +
                   sD[2][pslot][p][2];
    }
  }
}

// Fallback (only if ws_size is unexpectedly tiny): correctness-first.
__global__ __launch_bounds__(256) void render_lds_kernel(
    const float* __restrict__ mu, const float* __restrict__ cov,
    const float* __restrict__ opacity, const float* __restrict__ color,
    const int* __restrict__ tile_idx, float* __restrict__ out) {
  __shared__ float4 sA[K];
  __shared__ float4 sB[K];
  __shared__ float sC[K];
  int blk = blockIdx.x;
  int tile = blk >> 4;
  int t = threadIdx.x;
  {
    int n = tile_idx[tile * K + t];
    float a = cov[4 * n + 0];
    float b = cov[4 * n + 1];
    float c = cov[4 * n + 2];
    float d = cov[4 * n + 3];
    float det = fmaxf(a * d - b * c, 1e-6f);
    const float LOG2E = 1.4426950408889634f;
    float s = -0.5f * LOG2E / det;
    sA[t] = make_float4(mu[2 * n], mu[2 * n + 1], s * d, -s * (b + c));
    sB[t] = make_float4(s * a, log2f(fmaxf(opacity[n], 1e-30f)),
                        color[3 * n], color[3 * n + 1]);
    sC[t] = color[3 * n + 2];
  }
  __syncthreads();
  int chunk = blk & 15;
  int p = chunk * 256 + t;
  int ly = p >> 6;
  int lx = p & 63;
  int ty = tile >> 3;
  int tx = tile & 7;
  float px = (float)(tx * 64 + lx) + 0.5f;
  float py = (float)(ty * 64 + ly) + 0.5f;
  float accr = 0.f, accg = 0.f, accb = 0.f, S = 0.f;
#pragma unroll 4
  for (int k = 0; k < K; ++k) {
    float4 A = sA[k];
    float4 B = sB[k];
    float cb = sC[k];
    float dx = px - A.x;
    float dy = py - A.y;
    float base = fmaf(A.z * dx, dx, B.y);
    float mm = fmaf(dy, fmaf(B.x, dy, A.w * dx), base);
    float a = fminf(fmaxf(__builtin_amdgcn_exp2f(mm), 0.01f), 0.99f);
    float w = fmaf(-a, S, a);
    accr = fmaf(w, B.z, accr);
    accg = fmaf(w, B.w, accg);
    accb = fmaf(w, cb, accb);
    S += a;
  }
  int x = tx * 64 + lx;
  int y = ty * 64 + ly;
  size_t o = ((size_t)y * IMG_W + x) * 3;
  out[o + 0] = accr;
  out[o + 1] = accg;
  out[o + 2] = accb;
}

extern "C" void kernel_launch(void* const* d_in, const int* in_sizes, int n_in,
                              void* d_out, int out_size, void* d_ws,
                              size_t ws_size, hipStream_t stream) {
  const float* mu = (const float*)d_in[0];
  const float* cov = (const float*)d_in[1];
  const float* opacity = (const float*)d_in[2];
  const float* color = (const float*)d_in[3];
  const int* tile_idx = (const int*)d_in[4];
  float* out = (float*)d_out;

  const size_t need = (size_t)(OFF_MASK + T * 16 * 8) * 4;  // ~1.15 MB

  if (ws_size >= need) {
    float* ws = (float*)d_ws;
    pack_kernel<<<T, 256, 0, stream>>>(mu, cov, opacity, color, tile_idx, ws);
    render_kernel<<<T * 8, 512, 0, stream>>>(ws, out);
  } else {
    render_lds_kernel<<<T * 16, 256, 0, stream>>>(mu, cov, opacity, color,
                                                  tile_idx, out);
  }
}

// Round 8
// 68.873 us; speedup vs baseline: 1.3109x; 1.0579x over previous
//
#include <hip/hip_runtime.h>
#include <math.h>

#define TS 64
#define T 64
#define K 256
#define NSEG 4
#define KSEG 64
#define IMG_W 512

// Single fused kernel: 512 blocks x 512 threads, 2 blocks/CU.
//
// Stage (tid<256): gather gaussian tid of this block's tile, build LDS
// records + conservative cull radius:
//   alpha_raw = op*exp(-0.5*maha) = exp2(ea*dx^2 + eb*dx*dy + ed*dy^2 + lop)
//   s = -0.5*log2(e)/det: ea=s*d, eb=-s*(b+c), ed=s*a, lop=log2(op)
//   r^2 = 2*ln(op/0.01)*(a+d): beyond it maha >= d2/(a+d) forces
//   op*exp(-maha/2) <= 0.01 -> clip == 0.01f bit-exactly.
// Dual prefix scan (threads 0-255: col; 256-511: k*col) -> sPA/sPK, enabling
// O(1) compositing of a "far run" [i,j) where every alpha == 0.01:
//   local trans is affine in k:
//   dC = 0.01*[(1-S)*P1 - 0.01*(Pk - i*P1)],  dS = 0.01*len.
//
// Render: seg = tid>>7 handles k in [seg*64, seg*64+64); wave = 64 cols x
// 4-row band; its 64-bit near-mask comes from one __ballot (lane l tests
// gaussian kb+l vs the band rect). ~1-3 near gaussians get full math; far
// stretches collapse to runs.
// Segment combine: C = C_0 + sum_{s>=1}(C_s - S_prev(s)*A_s).
__global__ __launch_bounds__(512, 4) void render_all(
    const float* __restrict__ mu, const float* __restrict__ cov,
    const float* __restrict__ opacity, const float* __restrict__ color,
    const int* __restrict__ tile_idx, float* __restrict__ out) {
  __shared__ float4 sA[K];     // mux, muy, ea, eb
  __shared__ float4 sB[K];     // ed, lop, cr, cg
  __shared__ float sC[K];      // cb
  __shared__ float sR[K];      // r2
  __shared__ float4 sbuf[2 * K];  // scan working: [0,256)=col, [256,512)=k*col
  __shared__ float4 sPA[K + 1];
  __shared__ float4 sPK[K + 1];
  __shared__ float sS[NSEG][128][4];
  __shared__ float sD[3][128][4][3];

  int tid = threadIdx.x;
  int blk = blockIdx.x;
  int tile = blk & 63;   // XCD affinity: tile%8 == blk%8
  int chunk = blk >> 6;  // 0..7

  if (tid < K) {
    int n = tile_idx[tile * K + tid];
    float a = cov[4 * n + 0];
    float b = cov[4 * n + 1];
    float c = cov[4 * n + 2];
    float d = cov[4 * n + 3];
    float det = fmaxf(a * d - b * c, 1e-6f);
    const float LOG2E = 1.4426950408889634f;
    float s = -0.5f * LOG2E / det;
    float mx = mu[2 * n], my = mu[2 * n + 1];
    float lop = log2f(fmaxf(opacity[n], 1e-30f));
    float cr = color[3 * n], cg = color[3 * n + 1], cb = color[3 * n + 2];
    sA[tid] = make_float4(mx, my, s * d, -s * (b + c));
    sB[tid] = make_float4(s * a, lop, cr, cg);
    sC[tid] = cb;
    float r2 = 1.3862943611f * (lop + 6.6438561898f) * (a + d);
    sR[tid] = r2 * 1.0001f + 1e-3f;
    sbuf[tid] = make_float4(cr, cg, cb, 0.f);
    float fk = (float)tid;
    sbuf[K + tid] = make_float4(fk * cr, fk * cg, fk * cb, 0.f);
  }
  __syncthreads();

  // Dual Hillis-Steele scan: lower half of block scans col, upper scans k*col.
  int lane256 = tid & 255;
  float4* mybuf = sbuf + (tid & 256);
  for (int off = 1; off < K; off <<= 1) {
    float4 t;
    bool act = lane256 >= off;
    if (act) t = mybuf[lane256 - off];
    __syncthreads();
    if (act) {
      float4 u = mybuf[lane256];
      mybuf[lane256] = make_float4(u.x + t.x, u.y + t.y, u.z + t.z, 0.f);
    }
    __syncthreads();
  }
  if (tid < K) {
    sPA[tid + 1] = sbuf[tid];
  } else {
    sPK[lane256 + 1] = sbuf[K + lane256];
  }
  if (tid == 0) {
    sPA[0] = make_float4(0.f, 0.f, 0.f, 0.f);
    sPK[0] = make_float4(0.f, 0.f, 0.f, 0.f);
  }
  __syncthreads();

  int seg = __builtin_amdgcn_readfirstlane(tid >> 7);  // 0..3, wave-uniform
  int pslot = tid & 127;
  int lx = pslot & 63;
  int bnd = __builtin_amdgcn_readfirstlane(chunk * 2 + ((tid >> 6) & 1));
  int ty = tile >> 3, tx = tile & 7;
  int ly0 = bnd * 4;
  float px = (float)(tx * TS + lx) + 0.5f;
  float py0 = (float)(ty * TS + ly0) + 0.5f;
  const int kb = seg * KSEG;

  // Near-mask for this wave's (seg, band): lane l tests gaussian kb+l.
  unsigned long long m;
  {
    int l = tid & 63;
    float4 Ag = sA[kb + l];
    float r2 = sR[kb + l];
    float x0 = tx * TS + 0.5f, x1 = tx * TS + 63.5f;
    float y0 = py0, y1 = py0 + 3.0f;
    float dxm = fmaxf(fmaxf(Ag.x - x1, x0 - Ag.x), 0.f);
    float dym = fmaxf(fmaxf(Ag.y - y1, y0 - Ag.y), 0.f);
    float d2 = fmaf(dxm, dxm, dym * dym);
    m = __ballot(d2 < r2);
  }

  float C[4][3] = {};
  float An[4][3] = {};
  float Af[3] = {0.f, 0.f, 0.f};
  float S[4] = {};

  int i = kb;
  while (true) {
    int j = (m != 0ULL) ? (kb + (int)__builtin_ctzll(m)) : (kb + KSEG);
    if (j > i) {  // far run [i, j): every alpha == 0.01 exactly
      float len = (float)(j - i);
      float4 paj = sPA[j], pai = sPA[i];
      float4 pkj = sPK[j], pki = sPK[i];
      float P1r = paj.x - pai.x, P1g = paj.y - pai.y, P1b = paj.z - pai.z;
      float fi = (float)i;
      float Rr = -1e-4f * fmaf(-fi, P1r, pkj.x - pki.x);
      float Rg = -1e-4f * fmaf(-fi, P1g, pkj.y - pki.y);
      float Rb = -1e-4f * fmaf(-fi, P1b, pkj.z - pki.z);
      Af[0] = fmaf(0.01f, P1r, Af[0]);
      Af[1] = fmaf(0.01f, P1g, Af[1]);
      Af[2] = fmaf(0.01f, P1b, Af[2]);
#pragma unroll
      for (int p = 0; p < 4; ++p) {
        float t = fmaf(-0.01f, S[p], 0.01f);  // 0.01*(1 - S_local)
        C[p][0] = fmaf(t, P1r, C[p][0]) + Rr;
        C[p][1] = fmaf(t, P1g, C[p][1]) + Rg;
        C[p][2] = fmaf(t, P1b, C[p][2]) + Rb;
        S[p] = fmaf(0.01f, len, S[p]);
      }
    }
    if (j >= kb + KSEG) break;
    // near gaussian k = j: full math
    float4 A4 = sA[j];
    float4 B4 = sB[j];
    float cbv = sC[j];
    float dx = px - A4.x;
    float tb = A4.w * dx;
    float base = fmaf(A4.z * dx, dx, B4.y);
    float dy = py0 - A4.y;
#pragma unroll
    for (int p = 0; p < 4; ++p) {
      float dyp = dy + (float)p;
      float mm = fmaf(dyp, fmaf(B4.x, dyp, tb), base);
      float al =
          __builtin_amdgcn_fmed3f(__builtin_amdgcn_exp2f(mm), 0.01f, 0.99f);
      float w = fmaf(-al, S[p], al);
      C[p][0] = fmaf(w, B4.z, C[p][0]);
      C[p][1] = fmaf(w, B4.w, C[p][1]);
      C[p][2] = fmaf(w, cbv, C[p][2]);
      An[p][0] = fmaf(al, B4.z, An[p][0]);
      An[p][1] = fmaf(al, B4.w, An[p][1]);
      An[p][2] = fmaf(al, cbv, An[p][2]);
      S[p] += al;
    }
    m &= (m - 1ULL);
    i = j + 1;
  }

#pragma unroll
  for (int p = 0; p < 4; ++p) sS[seg][pslot][p] = S[p];
  __syncthreads();

  if (seg >= 1) {
#pragma unroll
    for (int p = 0; p < 4; ++p) {
      float Sp = sS[0][pslot][p];
      if (seg >= 2) Sp += sS[1][pslot][p];
      if (seg >= 3) Sp += sS[2][pslot][p];
      sD[seg - 1][pslot][p][0] = fmaf(-Sp, An[p][0] + Af[0], C[p][0]);
      sD[seg - 1][pslot][p][1] = fmaf(-Sp, An[p][1] + Af[1], C[p][1]);
      sD[seg - 1][pslot][p][2] = fmaf(-Sp, An[p][2] + Af[2], C[p][2]);
    }
  }
  __syncthreads();

  if (seg == 0) {
    int x = tx * TS + lx;
#pragma unroll
    for (int p = 0; p < 4; ++p) {
      int y = ty * TS + ly0 + p;
      size_t o = ((size_t)y * IMG_W + x) * 3;
      out[o + 0] = C[p][0] + sD[0][pslot][p][0] + sD[1][pslot][p][0] +
                   sD[2][pslot][p][0];
      out[o + 1] = C[p][1] + sD[0][pslot][p][1] + sD[1][pslot][p][1] +
                   sD[2][pslot][p][1];
      out[o + 2] = C[p][2] + sD[0][pslot][p][2] + sD[1][pslot][p][2] +
                   sD[2][pslot][p][2];
    }
  }
}

extern "C" void kernel_launch(void* const* d_in, const int* in_sizes, int n_in,
                              void* d_out, int out_size, void* d_ws,
                              size_t ws_size, hipStream_t stream) {
  const float* mu = (const float*)d_in[0];
  const float* cov = (const float*)d_in[1];
  const float* opacity = (const float*)d_in[2];
  const float* color = (const float*)d_in[3];
  const int* tile_idx = (const int*)d_in[4];
  float* out = (float*)d_out;
  (void)d_ws;
  (void)ws_size;

  render_all<<<T * 8, 512, 0, stream>>>(mu, cov, opacity, color, tile_idx,
                                        out);
}